// Round 8
// baseline (1133.833 us; speedup 1.0000x reference)
//
#include <hip/hip_runtime.h>
#include <math.h>

#define Bc 4
#define Nn 4000
#define KS 4096              // padded K stride for gemm2 operands
#define NP (16000000 + 4096)

typedef _Float16 half8 __attribute__((ext_vector_type(8)));
typedef float f32x4 __attribute__((ext_vector_type(4)));
typedef unsigned short u16x4 __attribute__((ext_vector_type(4)));

static __device__ __forceinline__ unsigned short f2h(float f) {
  _Float16 h = (_Float16)f;
  unsigned short u;
  __builtin_memcpy(&u, &h, 2);
  return u;
}
static __device__ __forceinline__ float h2f(unsigned short u) {
  _Float16 h;
  __builtin_memcpy(&h, &u, 2);
  return (float)h;
}
static __device__ __forceinline__ void gld16(const void* g, void* l) {
  __builtin_amdgcn_global_load_lds(
      (const __attribute__((address_space(1))) unsigned int*)g,
      (__attribute__((address_space(3))) unsigned int*)l, 16, 0, 0);
}

// ---------------------------------------------------------------------------
// K1: t_lhs[b,t] = sum_{n,f} x*U1[n] ; t_rhs[b,t] = sum_{n,f,g} x*U2[g,n]*U3[g]
// 4 threads per n (quad splits f); 63x4 grid for CU coverage.
__global__ __launch_bounds__(256) void k1_trhs(
    const float* __restrict__ x, const float* __restrict__ U1,
    const float* __restrict__ U2, const float* __restrict__ U3,
    float* __restrict__ tl, float* __restrict__ tr) {
  int b = blockIdx.y;
  int tid = threadIdx.x;
  int q = tid & 3;                       // f-quarter
  int n = blockIdx.x * 64 + (tid >> 2);
  float xs[16];
#pragma unroll
  for (int t = 0; t < 16; ++t) xs[t] = 0.f;
  float c1 = 0.f, c2 = 0.f;
  if (n < Nn) {
    const float* xr = x + ((size_t)b * Nn + n) * 256 + q * 64;  // 4 f rows
#pragma unroll
    for (int f = 0; f < 4; ++f) {
#pragma unroll
      for (int qq = 0; qq < 4; ++qq) {
        float4 v = *(const float4*)(xr + f * 16 + qq * 4);
        xs[qq * 4 + 0] += v.x; xs[qq * 4 + 1] += v.y;
        xs[qq * 4 + 2] += v.z; xs[qq * 4 + 3] += v.w;
      }
    }
    c1 = U1[n];
#pragma unroll
    for (int g = 0; g < 4; ++g) {
      int gg = q * 4 + g;
      c2 += U2[(size_t)gg * Nn + n] * U3[gg];
    }
  }
  // reduce partial xs / c2 across the 4 quad lanes (same n)
#pragma unroll
  for (int m = 1; m < 4; m <<= 1) {
    c2 += __shfl_xor(c2, m, 64);
#pragma unroll
    for (int t = 0; t < 16; ++t) xs[t] += __shfl_xor(xs[t], m, 64);
  }
  // each quad lane handles 4 t's
  float v1[4], v2[4];
#pragma unroll
  for (int i = 0; i < 4; ++i) {
    int t = q * 4 + i;
    v1[i] = c1 * xs[t];
    v2[i] = c2 * xs[t];
  }
#pragma unroll
  for (int off = 4; off < 64; off <<= 1) {
#pragma unroll
    for (int i = 0; i < 4; ++i) {
      v1[i] += __shfl_down(v1[i], off, 64);
      v2[i] += __shfl_down(v2[i], off, 64);
    }
  }
  int lane = tid & 63;
  if (lane < 4) {
#pragma unroll
    for (int i = 0; i < 4; ++i) {
      atomicAdd(&tl[b * 16 + lane * 4 + i], v1[i]);
      atomicAdd(&tr[b * 16 + lane * 4 + i], v2[i]);
    }
  }
}

// ---------------------------------------------------------------------------
// K2: temporal attention, output Ecol[b,s] = sum_t E[b,t,s]
__global__ __launch_bounds__(256) void k2_eattn(
    const float* __restrict__ tl, const float* __restrict__ tr,
    const float* __restrict__ be, const float* __restrict__ Ve,
    float* __restrict__ ecol) {
  int b = blockIdx.x;
  int tid = threadIdx.x;
  __shared__ float sig[256];
  __shared__ float Em[256];
  int s = tid >> 4, r = tid & 15;
  float z = tl[b * 16 + s] * tr[b * 16 + r] + be[s * 16 + r];
  sig[s * 16 + r] = 1.0f / (1.0f + __expf(-z));
  __syncthreads();
  float e = 0.f;
#pragma unroll
  for (int ss = 0; ss < 16; ++ss) e += Ve[s * 16 + ss] * sig[ss * 16 + r];
  Em[s * 16 + r] = e;
  __syncthreads();
  if (tid < 16) {
    float m = -1e30f;
#pragma unroll
    for (int rr = 0; rr < 16; ++rr) m = fmaxf(m, Em[tid * 16 + rr]);
    float ssum = 0.f;
    float ex[16];
#pragma unroll
    for (int rr = 0; rr < 16; ++rr) { ex[rr] = __expf(Em[tid * 16 + rr] - m); ssum += ex[rr]; }
    float inv = 1.0f / ssum;
#pragma unroll
    for (int rr = 0; rr < 16; ++rr) Em[tid * 16 + rr] = ex[rr] * inv;
  }
  __syncthreads();
  if (tid < 16) {
    float c = 0.f;
#pragma unroll
    for (int tt = 0; tt < 16; ++tt) c += Em[tt * 16 + tid];
    ecol[b * 16 + tid] = c;
  }
}

// ---------------------------------------------------------------------------
// K3: per (b,n) contractions over x row
__global__ __launch_bounds__(256) void k3_pern(
    const float* __restrict__ x, const float* __restrict__ ecol,
    const float* __restrict__ W1, const float* __restrict__ W2,
    const float* __restrict__ W3, const float* __restrict__ time_w,
    const float* __restrict__ time_b,
    float* __restrict__ xts, float* __restrict__ slhs,
    float* __restrict__ srhs, float* __restrict__ base) {
  __shared__ float tws[4096];
  __shared__ float W1s[16], W3s[16], Ecs[16], tbs[16], W2s[256];
  int tid = threadIdx.x;
  int b = blockIdx.y;
  for (int i = tid; i < 4096; i += 256) tws[i] = time_w[i];
  W2s[tid] = W2[tid & 255];
  if (tid < 16) {
    W1s[tid] = W1[tid]; W3s[tid] = W3[tid];
    Ecs[tid] = ecol[b * 16 + tid]; tbs[tid] = time_b[tid];
  }
  __syncthreads();
  int n = blockIdx.x * 256 + tid;
  if (n >= Nn) return;
  const float* xr = x + ((size_t)b * Nn + n) * 256;
  float xtsv[16], slv[16], xw3[16], to[16], resid[16];
#pragma unroll
  for (int i = 0; i < 16; ++i) { xtsv[i] = 0; slv[i] = 0; xw3[i] = 0; to[i] = 0; }
  for (int f = 0; f < 16; ++f) {
    float xf[16];
#pragma unroll
    for (int q = 0; q < 4; ++q) {
      float4 v = *(const float4*)(xr + f * 16 + q * 4);
      xf[q * 4 + 0] = v.x; xf[q * 4 + 1] = v.y; xf[q * 4 + 2] = v.z; xf[q * 4 + 3] = v.w;
    }
    float a = 0, c = 0, d = 0;
#pragma unroll
    for (int t2 = 0; t2 < 16; ++t2) {
      a += Ecs[t2] * xf[t2];
      c += W1s[t2] * xf[t2];
      d += W3s[t2] * xf[t2];
    }
    xtsv[f] = a; slv[f] = c; xw3[f] = d; resid[f] = xf[15];
#pragma unroll
    for (int o = 0; o < 16; ++o) {
      float acc = 0;
#pragma unroll
      for (int t2 = 0; t2 < 16; ++t2) acc += tws[o * 256 + f * 16 + t2] * xf[t2];
      to[o] += acc;
    }
  }
  size_t o16 = ((size_t)b * Nn + n) * 16;
#pragma unroll
  for (int g = 0; g < 16; ++g) {
    float acc = 0;
#pragma unroll
    for (int k2 = 0; k2 < 16; ++k2) acc += W2s[g * 16 + k2] * xw3[k2];
    srhs[o16 + g] = acc;
  }
#pragma unroll
  for (int i = 0; i < 16; ++i) {
    xts[o16 + i] = xtsv[i];
    slhs[o16 + i] = slv[i];
    base[o16 + i] = to[i] + tbs[i] + resid[i];
  }
}

// ---------------------------------------------------------------------------
// fconv: fp32 -> fp16 bulk convert, same flat layout (for lapH/bsH, 16M elems)
__global__ __launch_bounds__(256) void fconv(
    const float* __restrict__ src, unsigned short* __restrict__ dst) {
  size_t i = ((size_t)blockIdx.x * 256 + threadIdx.x) * 4;
  float4 v = *(const float4*)(src + i);
  u16x4 h;
  h.x = f2h(v.x); h.y = f2h(v.y); h.z = f2h(v.z); h.w = f2h(v.w);
  *(u16x4*)(dst + i) = h;
}

// ---------------------------------------------------------------------------
// vconv2: Vs (4000x4000 fp32) -> Vh (4096x4096 fp16), zero-padded both dims.
__global__ __launch_bounds__(256) void vconv2(
    const float* __restrict__ Vs, unsigned short* __restrict__ Vh) {
  int row = blockIdx.y;
  int col = blockIdx.x * 1024 + threadIdx.x * 4;
  u16x4 h;
  if (row < Nn && col < Nn) {  // col aligned: 4000 % 4 == 0
    float4 v = *(const float4*)(Vs + (size_t)row * Nn + col);
    h.x = f2h(v.x); h.y = f2h(v.y); h.z = f2h(v.z); h.w = f2h(v.w);
  } else {
    h.x = 0; h.y = 0; h.z = 0; h.w = 0;
  }
  *(u16x4*)(Vh + (size_t)row * KS + col) = h;
}

// ---------------------------------------------------------------------------
// tsconv: ts[b][n][f] fp32 -> tsT[(b*16+f)][n] fp16 (B-operand for chebm)
__global__ __launch_bounds__(256) void tsconv(
    const float* __restrict__ ts, unsigned short* __restrict__ tsT) {
  int n = blockIdx.x * 256 + threadIdx.x;
  int col = blockIdx.y;  // 0..63 = (b<<4)|f
  if (n >= Nn) return;
  int b = col >> 4, f = col & 15;
  tsT[(size_t)col * Nn + n] = f2h(ts[((size_t)b * Nn + n) * 16 + f]);
}

// ---------------------------------------------------------------------------
// GEMM1: P[m,k] = sigmoid(slhs[b,m]·srhs[b,k] + bs[m,k]); store P^T fp16
// with row stride KS (pad k-cols left poisoned; they multiply Vh's zero pad).
__global__ __launch_bounds__(256) void gemm1_P(
    const float* __restrict__ slhs, const float* __restrict__ srhs,
    const unsigned short* __restrict__ bsH, unsigned short* __restrict__ PhT, int b) {
  __shared__ float Ms[64][17];
  __shared__ float Cs[64][17];
  __shared__ float Pt[64][65];
  int tid = threadIdx.x;
  int m0 = blockIdx.y * 64, k0 = blockIdx.x * 64;
  int lr = tid >> 2, lq = (tid & 3) << 2;
  {
    int gm = m0 + lr; if (gm > Nn - 1) gm = Nn - 1;
    float4 v = *(const float4*)(slhs + ((size_t)b * Nn + gm) * 16 + lq);
    Ms[lr][lq + 0] = v.x; Ms[lr][lq + 1] = v.y; Ms[lr][lq + 2] = v.z; Ms[lr][lq + 3] = v.w;
    int gk = k0 + lr; if (gk > Nn - 1) gk = Nn - 1;
    float4 w = *(const float4*)(srhs + ((size_t)b * Nn + gk) * 16 + lq);
    Cs[lr][lq + 0] = w.x; Cs[lr][lq + 1] = w.y; Cs[lr][lq + 2] = w.z; Cs[lr][lq + 3] = w.w;
  }
  __syncthreads();
  int tx = tid & 15, ty = tid >> 4;
  float acc[4][4] = {};
#pragma unroll
  for (int f = 0; f < 16; ++f) {
    float a4[4], b4[4];
#pragma unroll
    for (int i = 0; i < 4; ++i) a4[i] = Ms[ty * 4 + i][f];
#pragma unroll
    for (int j = 0; j < 4; ++j) b4[j] = Cs[tx * 4 + j][f];
#pragma unroll
    for (int i = 0; i < 4; ++i)
#pragma unroll
      for (int j = 0; j < 4; ++j) acc[i][j] += a4[i] * b4[j];
  }
#pragma unroll
  for (int i = 0; i < 4; ++i) {
    int m = m0 + ty * 4 + i;
    int k = k0 + tx * 4;
    float bv[4] = {0.f, 0.f, 0.f, 0.f};
    if (m < Nn) {
      if (k + 3 < Nn) {
        u16x4 t4 = *(const u16x4*)(bsH + (size_t)m * Nn + k);
        bv[0] = h2f(t4.x); bv[1] = h2f(t4.y); bv[2] = h2f(t4.z); bv[3] = h2f(t4.w);
      } else {
        for (int j = 0; j < 4; ++j)
          if (k + j < Nn) bv[j] = h2f(bsH[(size_t)m * Nn + k + j]);
      }
    }
#pragma unroll
    for (int j = 0; j < 4; ++j) {
      float z = acc[i][j] + bv[j];
      Pt[ty * 4 + i][tx * 4 + j] = 1.f / (1.f + __expf(-z));
    }
  }
  __syncthreads();
#pragma unroll
  for (int i = 0; i < 4; ++i) {
    int kl = ty * 4 + i;
    int ml = tx * 4;
    int gm = m0 + ml;
    u16x4 h;
    h.x = f2h(Pt[ml + 0][kl]);
    h.y = f2h(Pt[ml + 1][kl]);
    h.z = f2h(Pt[ml + 2][kl]);
    h.w = f2h(Pt[ml + 3][kl]);
    size_t off = (size_t)(k0 + kl) * KS + gm;
    if (gm + 3 < Nn) {
      *(u16x4*)(PhT + off) = h;
    } else {
      unsigned short hv[4] = {h.x, h.y, h.z, h.w};
      for (int q = 0; q < 4; ++q)
        if (gm + q < Nn) PhT[off + q] = hv[q];
    }
  }
}

// ---------------------------------------------------------------------------
// GEMM2: 256x256 tile, 8-wave, 2-phase/K-tile (r8: merged from 4-phase),
// counted vmcnt, drain-at-end.  Phase = {STG 2 units -> 12 ds_reads ->
// 32-MFMA cluster (compiler interleaves counted lgkm waits) -> lgkmcnt(0)
// -> vmcnt(8) -> barrier}.  Halves barriers/drains per K-tile vs r7.
// Ledger: kh1(G) staged phA(G-1), 8 loads since -> vmcnt(8) at phA end;
// kh0(G+1) staged phB(G-1), 8 since -> vmcnt(8) at phB end; prologue
// vmcnt(12).  WAR: each phase's reads drain at own lgkm0+barrier before
// the overwriting STG issues next phase.  G=0 dups / G>=62 clamped dummies
// write never-read buffers (same as verified 4-phase).
// Bank-conflict-free swizzle (r4-verified): store granule g^((row>>1)&3) via
// pre-swizzled global source (linear LDS dest, m104); read gr=qd^((ml>>1)&3).
__global__ __launch_bounds__(512, 2) void gemm2_mfma(
    const unsigned short* __restrict__ Vh, const unsigned short* __restrict__ PhT,
    float* __restrict__ SP, unsigned int* __restrict__ rmaxu) {
  __shared__ unsigned short Ah[2][2][8192];
  __shared__ unsigned short Bh[2][2][8192];
  int t = threadIdx.x;
  int bid = blockIdx.x;
  int wg = (bid & 7) * 32 + (bid >> 3);       // bijective XCD swizzle (256%8==0)
  int row0 = (wg >> 4) * 256, col0 = (wg & 15) * 256;

  int sr = t >> 2, sg = t & 3;
  int ssw = sg ^ ((t >> 3) & 3);
  size_t a0 = (size_t)(row0 + sr) * KS + ssw * 8;
  size_t a1 = (size_t)(row0 + 128 + sr) * KS + ssw * 8;
  size_t b0 = (size_t)(col0 + sr) * KS + ssw * 8;
  size_t b1 = (size_t)(col0 + 128 + sr) * KS + ssw * 8;
  int ld0 = t * 8, ld1 = 4096 + t * 8;        // LDS dest short-index (lane-linear)

  int lane = t & 63, wid = t >> 6;
  int wm = (wid >> 2) * 128, wn = (wid & 3) * 64;
  int ml = lane & 15, qd = lane >> 4;
  int gr = qd ^ ((ml >> 1) & 3);
  int aro[8], bro[4];
#pragma unroll
  for (int i = 0; i < 8; ++i) aro[i] = (wm + ml + i * 16) * 32 + gr * 8;
#pragma unroll
  for (int j = 0; j < 4; ++j) bro[j] = (wn + ml + j * 16) * 32 + gr * 8;

  f32x4 acc[8][4] = {};

#define STG(P, X, bf, kh, o0, o1, kt)                          \
  do {                                                         \
    size_t c_ = (size_t)(kt) * 64 + (kh) * 32;                 \
    gld16(P + (o0) + c_, &X[bf][kh][ld0]);                     \
    gld16(P + (o1) + c_, &X[bf][kh][ld1]);                     \
  } while (0)
#define LGKM0() asm volatile("s_waitcnt lgkmcnt(0)" ::: "memory")
#define VM8()   asm volatile("s_waitcnt vmcnt(8)" ::: "memory")
#define BARR()  __builtin_amdgcn_s_barrier()

  // prologue: tiles 0 and 1 fully staged (16 loads)
  STG(Vh, Ah, 0, 0, a0, a1, 0); STG(PhT, Bh, 0, 0, b0, b1, 0);
  STG(Vh, Ah, 0, 1, a0, a1, 0); STG(PhT, Bh, 0, 1, b0, b1, 0);
  STG(Vh, Ah, 1, 0, a0, a1, 1); STG(PhT, Bh, 1, 0, b0, b1, 1);
  STG(Vh, Ah, 1, 1, a0, a1, 1); STG(PhT, Bh, 1, 1, b0, b1, 1);
  asm volatile("s_waitcnt vmcnt(12)" ::: "memory");  // kh0(0) landed
  BARR();

#pragma unroll 1
  for (int G = 0; G < 64; ++G) {
    int cb = G & 1, nb = cb ^ 1;
    int tn1 = (G + 1 < 64) ? G + 1 : 63;   // clamped dummy keeps vmcnt uniform
    int tn2 = (G + 2 < 64) ? G + 2 : 63;
    half8 av[8], bv[4];
    // ---- phase A: consume kh0(G); stage kh1(G+1)
    STG(Vh, Ah, nb, 1, a0, a1, tn1);
    STG(PhT, Bh, nb, 1, b0, b1, tn1);
#pragma unroll
    for (int j = 0; j < 4; ++j) bv[j] = *(const half8*)&Bh[cb][0][bro[j]];
#pragma unroll
    for (int i = 0; i < 8; ++i) av[i] = *(const half8*)&Ah[cb][0][aro[i]];
    __builtin_amdgcn_s_setprio(1);
#pragma unroll
    for (int i = 0; i < 8; ++i)
#pragma unroll
      for (int j = 0; j < 4; ++j)
        acc[i][j] = __builtin_amdgcn_mfma_f32_16x16x32_f16(av[i], bv[j], acc[i][j], 0, 0, 0);
    __builtin_amdgcn_s_setprio(0);
    LGKM0();
    VM8();                              // kh1(G) landed
    BARR();
    // ---- phase B: consume kh1(G); stage kh0(G+2)
    STG(Vh, Ah, cb, 0, a0, a1, tn2);
    STG(PhT, Bh, cb, 0, b0, b1, tn2);
#pragma unroll
    for (int j = 0; j < 4; ++j) bv[j] = *(const half8*)&Bh[cb][1][bro[j]];
#pragma unroll
    for (int i = 0; i < 8; ++i) av[i] = *(const half8*)&Ah[cb][1][aro[i]];
    __builtin_amdgcn_s_setprio(1);
#pragma unroll
    for (int i = 0; i < 8; ++i)
#pragma unroll
      for (int j = 0; j < 4; ++j)
        acc[i][j] = __builtin_amdgcn_mfma_f32_16x16x32_f16(av[i], bv[j], acc[i][j], 0, 0, 0);
    __builtin_amdgcn_s_setprio(0);
    LGKM0();
    VM8();                              // kh0(G+1) landed
    BARR();
  }
#undef STG
#undef LGKM0
#undef VM8
#undef BARR

  // epilogue: C/D layout col=lane&15, row=(lane>>4)*4+reg [m89]; store + row max
#pragma unroll
  for (int i = 0; i < 8; ++i) {
#pragma unroll
    for (int r = 0; r < 4; ++r) {
      int grow = row0 + wm + i * 16 + qd * 4 + r;
      if (grow >= Nn) continue;
      float rowmax = -3.0e38f;
#pragma unroll
      for (int j = 0; j < 4; ++j) {
        int gcol = col0 + wn + j * 16 + ml;
        if (gcol < Nn) {
          float v = acc[i][j][r];
          SP[(size_t)grow * Nn + gcol] = v;
          rowmax = fmaxf(rowmax, v);
        }
      }
#pragma unroll
      for (int mk = 1; mk < 16; mk <<= 1)
        rowmax = fmaxf(rowmax, __shfl_xor(rowmax, mk, 64));
      if (ml == 0) {
        unsigned u = __float_as_uint(rowmax);
        u = (u & 0x80000000u) ? ~u : (u | 0x80000000u);
        atomicMax(rmaxu + grow, u);
      }
    }
  }
}

// ---------------------------------------------------------------------------
// txsum (MFMA rewrite): ts0[b,n,f] += sum_{k in chunk} exp(SP[n,k]-rm[n])*X[k,f]
// Wave = 16 rows x 800-k chunk.  Lane exps 8 SP values -> half8 A-frag
// (row=lane&15, k=(lane>>4)*8+j, same verified mapping as gemm2).  X staged
// once per block as fp16 XT[f][824-padded k] -> b128 B-frags.  25 MFMAs.
// lsum via per-lane exp-sum reduced over qd lanes.  Split-K grid (63,5).
// 4000 = 62*64+32: out-of-range rows only occur as WHOLE waves (discarded).
__global__ __launch_bounds__(256) void txsum_sp(
    const float* __restrict__ SP, const float* __restrict__ xts,
    const unsigned int* __restrict__ rmaxu, float* __restrict__ lsum,
    float* __restrict__ ts0, int b) {
  __shared__ unsigned short XT[16][824];   // [f][k] fp16, pad->(<=2-way conflicts)
  int tid = threadIdx.x;
  int kbase = blockIdx.y * 800;            // 5 chunks x 800 = 4000, 800 = 25*32
  // stage X^T as fp16 (cooperative, one-time)
  for (int i4 = tid; i4 < 3200; i4 += 256) {
    int k = i4 >> 2, f4 = (i4 & 3) << 2;
    float4 v = *(const float4*)(xts + ((size_t)b * Nn + kbase + k) * 16 + f4);
    XT[f4 + 0][k] = f2h(v.x); XT[f4 + 1][k] = f2h(v.y);
    XT[f4 + 2][k] = f2h(v.z); XT[f4 + 3][k] = f2h(v.w);
  }
  __syncthreads();
  int lane = tid & 63, wid = tid >> 6;
  int ml = lane & 15, qd = lane >> 4;
  int n0 = blockIdx.x * 64 + wid * 16;
  int nr = n0 + ml;
  int nrc = nr < Nn ? nr : Nn - 1;
  unsigned u = rmaxu[nrc];
  u = (u & 0x80000000u) ? (u ^ 0x80000000u) : ~u;
  float rm = __uint_as_float(u);
  const float* spr = SP + (size_t)nrc * Nn + kbase + qd * 8;
  f32x4 acc = {0.f, 0.f, 0.f, 0.f};
  float lpart = 0.f;
#pragma unroll 1
  for (int ks = 0; ks < 25; ++ks) {
    float4 v0 = *(const float4*)(spr + ks * 32);
    float4 v1 = *(const float4*)(spr + ks * 32 + 4);
    float e0 = __expf(v0.x - rm), e1 = __expf(v0.y - rm);
    float e2 = __expf(v0.z - rm), e3 = __expf(v0.w - rm);
    float e4 = __expf(v1.x - rm), e5 = __expf(v1.y - rm);
    float e6 = __expf(v1.z - rm), e7 = __expf(v1.w - rm);
    lpart += ((e0 + e1) + (e2 + e3)) + ((e4 + e5) + (e6 + e7));
    half8 a_h, b_h;
    a_h[0] = (_Float16)e0; a_h[1] = (_Float16)e1;
    a_h[2] = (_Float16)e2; a_h[3] = (_Float16)e3;
    a_h[4] = (_Float16)e4; a_h[5] = (_Float16)e5;
    a_h[6] = (_Float16)e6; a_h[7] = (_Float16)e7;
    b_h = *(const half8*)&XT[ml][ks * 32 + qd * 8];
    acc = __builtin_amdgcn_mfma_f32_16x16x32_f16(a_h, b_h, acc, 0, 0, 0);
  }
  // lsum: reduce exp-sum over the 4 lanes sharing row ml
  lpart += __shfl_xor(lpart, 16, 64);
  lpart += __shfl_xor(lpart, 32, 64);
  if (qd == 0 && nr < Nn) atomicAdd(&lsum[nr], lpart);
  // C/D layout: col(f)=lane&15, row n = n0 + qd*4 + r  [m89]
#pragma unroll
  for (int r = 0; r < 4; ++r) {
    int n = n0 + qd * 4 + r;
    if (n < Nn) atomicAdd(&ts0[((size_t)b * Nn + n) * 16 + ml], acc[r]);
  }
}

// ---------------------------------------------------------------------------
// nrm_k: ts0[b,n,f] /= lsum[b,n]
__global__ __launch_bounds__(256) void nrm_k(
    float* __restrict__ ts0, const float* __restrict__ lsum) {
  int tid = threadIdx.x;
  int b = blockIdx.y;
  int n = blockIdx.x * 16 + (tid >> 4);
  size_t i = ((size_t)b * Nn + n) * 16 + (tid & 15);
  ts0[i] = ts0[i] / lsum[b * Nn + n];
}

// ---------------------------------------------------------------------------
// chebm (MFMA, split-K x5): Cout[(c>>4)*Nn+row][c&15] += sum_{k in chunk}
//   lapH[row][k]*tsT[c][k].  Scale and Chebyshev C0-subtraction are folded
//   into ky_k (T2 recombination), enabling pure atomicAdd split-K.
//   K=4000=125*32 tiles; 5 chunks of 25 tiles -> grid (63,5)=315 blocks.
__global__ __launch_bounds__(256) void chebm(
    const unsigned short* __restrict__ lapH, const unsigned short* __restrict__ tsT,
    float* __restrict__ Cout) {
  __shared__ unsigned short Ah[64 * 32];
  __shared__ unsigned short Bh[64 * 32];
  int t = threadIdx.x;
  int row0 = blockIdx.x * 64;
  int kc0 = blockIdx.y * 25 * 32;
  int kc1 = kc0 + 25 * 32;
  int arow = row0 + (t >> 2); if (arow > Nn - 1) arow = Nn - 1;
  size_t a_base = (size_t)arow * Nn + (t & 3) * 8;
  size_t b_base = (size_t)(t >> 2) * Nn + (t & 3) * 8;

  int lane = t & 63;
  int wid = t >> 6;
  int wm = (wid >> 1) * 32, wn = (wid & 1) * 32;
  int ml = lane & 15, qd = lane >> 4;
  int aoff = (wm + ml) * 32 + qd * 8;
  int boff = (wn + ml) * 32 + qd * 8;

  f32x4 acc[2][2] = {};

  for (int k0 = kc0; k0 < kc1; k0 += 32) {
    gld16(lapH + a_base + k0, &Ah[t * 8]);
    gld16(tsT + b_base + k0, &Bh[t * 8]);
    __syncthreads();
    half8 a_h[2], b_h[2];
#pragma unroll
    for (int i = 0; i < 2; ++i) a_h[i] = *(const half8*)&Ah[aoff + i * 512];
#pragma unroll
    for (int j = 0; j < 2; ++j) b_h[j] = *(const half8*)&Bh[boff + j * 512];
#pragma unroll
    for (int i = 0; i < 2; ++i)
#pragma unroll
      for (int j = 0; j < 2; ++j)
        acc[i][j] = __builtin_amdgcn_mfma_f32_16x16x32_f16(a_h[i], b_h[j], acc[i][j], 0, 0, 0);
    __syncthreads();
  }
#pragma unroll
  for (int i = 0; i < 2; ++i)
#pragma unroll
    for (int j = 0; j < 2; ++j) {
      int gcol = wn + j * 16 + ml;
      int b = gcol >> 4, f = gcol & 15;
#pragma unroll
      for (int r = 0; r < 4; ++r) {
        int grow = row0 + wm + i * 16 + qd * 4 + r;
        if (grow < Nn) {
          size_t idx = ((size_t)b * Nn + grow) * 16 + f;
          atomicAdd(&Cout[idx], acc[i][j][r]);
        }
      }
    }
}

// ---------------------------------------------------------------------------
// K_y: Chebyshev recombination with split-K-raw ts2 (ts2raw = lap·ts1):
//   Tx2 = 2·lap·Tx1 − Tx0  =>  contribution T0·(CW0−CW2) + T1·CW1 + 2·T2raw·CW2
// y = (1/16)*sum + base ; accumulate LN stats
__global__ __launch_bounds__(256) void ky_k(
    const float* __restrict__ ts0, const float* __restrict__ ts1,
    const float* __restrict__ ts2, const float* __restrict__ cw,
    const float* __restrict__ base, float* __restrict__ ybuf,
    float* __restrict__ lnacc) {
  __shared__ float T0[256], T1[256], T2[256], CW[768];
  __shared__ float rs[256], rq[256];
  int tid = threadIdx.x;
  int b = blockIdx.y;
  size_t base_i = ((size_t)b * Nn + blockIdx.x * 16) * 16;
  T0[tid] = ts0[base_i + tid];
  T1[tid] = ts1[base_i + tid];
  T2[tid] = ts2[base_i + tid];
  for (int i = tid; i < 768; i += 256) CW[i] = cw[i];
  __syncthreads();
  int r = tid >> 4, o = tid & 15;
  float acc = 0.f;
#pragma unroll
  for (int f2 = 0; f2 < 16; ++f2) {
    float c2 = CW[512 + f2 * 16 + o];
    acc += T0[r * 16 + f2] * (CW[f2 * 16 + o] - c2);
    acc += T1[r * 16 + f2] * CW[256 + f2 * 16 + o];
    acc += (2.0f * T2[r * 16 + f2]) * c2;
  }
  float y = acc * 0.0625f + base[base_i + tid];
  ybuf[base_i + tid] = y;
  rs[tid] = y; rq[tid] = y * y;
  __syncthreads();
  for (int s2 = 128; s2 > 0; s2 >>= 1) {
    if (tid < s2) { rs[tid] += rs[tid + s2]; rq[tid] += rq[tid + s2]; }
    __syncthreads();
  }
  if (tid == 0) {
    atomicAdd(&lnacc[b * 2 + 0], rs[0]);
    atomicAdd(&lnacc[b * 2 + 1], rq[0]);
  }
}

// ---------------------------------------------------------------------------
// K_ln: layernorm over (N,O) per batch + relu
__global__ __launch_bounds__(256) void kln_k(
    const float* __restrict__ ybuf, const float* __restrict__ lnacc,
    const float* __restrict__ lg, const float* __restrict__ lb,
    float* __restrict__ outp) {
  int tid = threadIdx.x;
  int b = blockIdx.y;
  size_t i = ((size_t)b * Nn + blockIdx.x * 16) * 16 + tid;
  size_t nz = (size_t)blockIdx.x * 256 + tid;
  const float inv = 1.0f / 64000.0f;
  float s = lnacc[b * 2 + 0], q = lnacc[b * 2 + 1];
  float mean = s * inv;
  float var = q * inv - mean * mean;
  float rstd = rsqrtf(var + 1e-5f);
  float v = (ybuf[i] - mean) * rstd * lg[nz] + lb[nz];
  outp[i] = fmaxf(v, 0.f);
}

// ---------------------------------------------------------------------------
extern "C" void kernel_launch(void* const* d_in, const int* in_sizes, int n_in,
                              void* d_out, int out_size, void* d_ws, size_t ws_size,
                              hipStream_t stream) {
  const float* x   = (const float*)d_in[0];
  const float* lap = (const float*)d_in[1];
  const float* W1  = (const float*)d_in[2];
  const float* W2  = (const float*)d_in[3];
  const float* W3  = (const float*)d_in[4];
  const float* bs  = (const float*)d_in[5];
  const float* Vs  = (const float*)d_in[6];
  const float* U1  = (const float*)d_in[7];
  const float* U2  = (const float*)d_in[8];
  const float* U3  = (const float*)d_in[9];
  const float* be  = (const float*)d_in[10];
  const float* Ve  = (const float*)d_in[11];
  const float* cw  = (const float*)d_in[12];
  const float* tw  = (const float*)d_in[13];
  const float* tb  = (const float*)d_in[14];
  const float* lg  = (const float*)d_in[15];
  const float* lb  = (const float*)d_in[16];
  float* ws = (float*)d_ws;
  float* SP = ws;  // NP floats
  unsigned short* Vh   = (unsigned short*)(ws + (size_t)NP);       // 4096*4096
  unsigned short* PhT  = Vh + (size_t)KS * KS;                     // 4096*4096
  unsigned short* lapH = PhT + (size_t)KS * KS;                    // 4000*4000
  unsigned short* bsH  = lapH + (size_t)Nn * Nn;                   // 4000*4000
  unsigned short* tsT  = bsH + (size_t)Nn * Nn;                    // 64*4000
  float* xts  = (float*)(tsT + 64 * Nn + 64);
  float* slhs = xts + 256000;
  float* srhs = slhs + 256000;
  float* base = srhs + 256000;
  float* ts0  = base + 256000;
  float* ts1  = ts0 + 256000;
  float* ts2  = ts1 + 256000;
  float* ybuf = ts2 + 256000;
  float* tl   = ybuf + 256000;  // B*16
  float* tr   = tl + 64;
  float* ecol = tr + 64;
  unsigned int* rmaxu = (unsigned int*)(ecol + 64);  // B*N
  float* lsum = (float*)(rmaxu + Bc * Nn);           // B*N
  float* lnacc = lsum + Bc * Nn;                     // B*2

  hipMemsetAsync(tl, 0, 128 * sizeof(float), stream);
  hipMemsetAsync(lnacc, 0, 8 * sizeof(float), stream);
  hipMemsetAsync(ts0, 0, 256000 * sizeof(float), stream);
  hipMemsetAsync(ts1, 0, 256000 * sizeof(float), stream);
  hipMemsetAsync(ts2, 0, 256000 * sizeof(float), stream);
  hipMemsetAsync(rmaxu, 0, Bc * Nn * sizeof(unsigned int), stream);
  hipMemsetAsync(lsum, 0, Bc * Nn * sizeof(float), stream);

  k1_trhs<<<dim3(63, 4), 256, 0, stream>>>(x, U1, U2, U3, tl, tr);
  k2_eattn<<<dim3(4), 256, 0, stream>>>(tl, tr, be, Ve, ecol);
  k3_pern<<<dim3(16, 4), 256, 0, stream>>>(x, ecol, W1, W2, W3, tw, tb,
                                           xts, slhs, srhs, base);
  vconv2<<<dim3(4, 4096), 256, 0, stream>>>(Vs, Vh);
  fconv<<<dim3(15625), 256, 0, stream>>>(lap, lapH);
  fconv<<<dim3(15625), 256, 0, stream>>>(bs, bsH);
  for (int b = 0; b < 4; ++b) {
    gemm1_P<<<dim3(63, 63), 256, 0, stream>>>(slhs, srhs, bsH, PhT, b);
    gemm2_mfma<<<dim3(256), 512, 0, stream>>>(Vh, PhT, SP, rmaxu + b * Nn);
    txsum_sp<<<dim3(63, 5), 256, 0, stream>>>(SP, xts, rmaxu + b * Nn,
                                              lsum + b * Nn, ts0, b);
  }
  nrm_k<<<dim3(250, 4), 256, 0, stream>>>(ts0, lsum);
  tsconv<<<dim3(16, 64), 256, 0, stream>>>(ts0, tsT);
  chebm<<<dim3(63, 5), 256, 0, stream>>>(lapH, tsT, ts1);
  tsconv<<<dim3(16, 64), 256, 0, stream>>>(ts1, tsT);
  chebm<<<dim3(63, 5), 256, 0, stream>>>(lapH, tsT, ts2);
  ky_k<<<dim3(250, 4), 256, 0, stream>>>(ts0, ts1, ts2, cw, base, ybuf, lnacc);
  kln_k<<<dim3(250, 4), 256, 0, stream>>>(ybuf, lnacc, lg, lb, (float*)d_out);
}

// Round 9
// 1073.900 us; speedup vs baseline: 1.0558x; 1.0558x over previous
//
#include <hip/hip_runtime.h>
#include <math.h>

#define Bc 4
#define Nn 4000
#define KS 4096              // padded K stride for gemm2 operands
#define NP (16000000 + 4096)

typedef _Float16 half8 __attribute__((ext_vector_type(8)));
typedef float f32x4 __attribute__((ext_vector_type(4)));
typedef unsigned short u16x4 __attribute__((ext_vector_type(4)));

static __device__ __forceinline__ unsigned short f2h(float f) {
  _Float16 h = (_Float16)f;
  unsigned short u;
  __builtin_memcpy(&u, &h, 2);
  return u;
}
static __device__ __forceinline__ float h2f(unsigned short u) {
  _Float16 h;
  __builtin_memcpy(&h, &u, 2);
  return (float)h;
}
static __device__ __forceinline__ void gld16(const void* g, void* l) {
  __builtin_amdgcn_global_load_lds(
      (const __attribute__((address_space(1))) unsigned int*)g,
      (__attribute__((address_space(3))) unsigned int*)l, 16, 0, 0);
}

// ---------------------------------------------------------------------------
// K1: t_lhs[b,t] = sum_{n,f} x*U1[n] ; t_rhs[b,t] = sum_{n,f,g} x*U2[g,n]*U3[g]
// 4 threads per n (quad splits f); 63x4 grid for CU coverage.
__global__ __launch_bounds__(256) void k1_trhs(
    const float* __restrict__ x, const float* __restrict__ U1,
    const float* __restrict__ U2, const float* __restrict__ U3,
    float* __restrict__ tl, float* __restrict__ tr) {
  int b = blockIdx.y;
  int tid = threadIdx.x;
  int q = tid & 3;                       // f-quarter
  int n = blockIdx.x * 64 + (tid >> 2);
  float xs[16];
#pragma unroll
  for (int t = 0; t < 16; ++t) xs[t] = 0.f;
  float c1 = 0.f, c2 = 0.f;
  if (n < Nn) {
    const float* xr = x + ((size_t)b * Nn + n) * 256 + q * 64;  // 4 f rows
#pragma unroll
    for (int f = 0; f < 4; ++f) {
#pragma unroll
      for (int qq = 0; qq < 4; ++qq) {
        float4 v = *(const float4*)(xr + f * 16 + qq * 4);
        xs[qq * 4 + 0] += v.x; xs[qq * 4 + 1] += v.y;
        xs[qq * 4 + 2] += v.z; xs[qq * 4 + 3] += v.w;
      }
    }
    c1 = U1[n];
#pragma unroll
    for (int g = 0; g < 4; ++g) {
      int gg = q * 4 + g;
      c2 += U2[(size_t)gg * Nn + n] * U3[gg];
    }
  }
  // reduce partial xs / c2 across the 4 quad lanes (same n)
#pragma unroll
  for (int m = 1; m < 4; m <<= 1) {
    c2 += __shfl_xor(c2, m, 64);
#pragma unroll
    for (int t = 0; t < 16; ++t) xs[t] += __shfl_xor(xs[t], m, 64);
  }
  // each quad lane handles 4 t's
  float v1[4], v2[4];
#pragma unroll
  for (int i = 0; i < 4; ++i) {
    int t = q * 4 + i;
    v1[i] = c1 * xs[t];
    v2[i] = c2 * xs[t];
  }
#pragma unroll
  for (int off = 4; off < 64; off <<= 1) {
#pragma unroll
    for (int i = 0; i < 4; ++i) {
      v1[i] += __shfl_down(v1[i], off, 64);
      v2[i] += __shfl_down(v2[i], off, 64);
    }
  }
  int lane = tid & 63;
  if (lane < 4) {
#pragma unroll
    for (int i = 0; i < 4; ++i) {
      atomicAdd(&tl[b * 16 + lane * 4 + i], v1[i]);
      atomicAdd(&tr[b * 16 + lane * 4 + i], v2[i]);
    }
  }
}

// ---------------------------------------------------------------------------
// K2: temporal attention, output Ecol[b,s] = sum_t E[b,t,s]
__global__ __launch_bounds__(256) void k2_eattn(
    const float* __restrict__ tl, const float* __restrict__ tr,
    const float* __restrict__ be, const float* __restrict__ Ve,
    float* __restrict__ ecol) {
  int b = blockIdx.x;
  int tid = threadIdx.x;
  __shared__ float sig[256];
  __shared__ float Em[256];
  int s = tid >> 4, r = tid & 15;
  float z = tl[b * 16 + s] * tr[b * 16 + r] + be[s * 16 + r];
  sig[s * 16 + r] = 1.0f / (1.0f + __expf(-z));
  __syncthreads();
  float e = 0.f;
#pragma unroll
  for (int ss = 0; ss < 16; ++ss) e += Ve[s * 16 + ss] * sig[ss * 16 + r];
  Em[s * 16 + r] = e;
  __syncthreads();
  if (tid < 16) {
    float m = -1e30f;
#pragma unroll
    for (int rr = 0; rr < 16; ++rr) m = fmaxf(m, Em[tid * 16 + rr]);
    float ssum = 0.f;
    float ex[16];
#pragma unroll
    for (int rr = 0; rr < 16; ++rr) { ex[rr] = __expf(Em[tid * 16 + rr] - m); ssum += ex[rr]; }
    float inv = 1.0f / ssum;
#pragma unroll
    for (int rr = 0; rr < 16; ++rr) Em[tid * 16 + rr] = ex[rr] * inv;
  }
  __syncthreads();
  if (tid < 16) {
    float c = 0.f;
#pragma unroll
    for (int tt = 0; tt < 16; ++tt) c += Em[tt * 16 + tid];
    ecol[b * 16 + tid] = c;
  }
}

// ---------------------------------------------------------------------------
// K3 (r9: quad-split): 4 threads per n, each owns 4 f-rows; grid 63x4.
// to[o] and srhs[g] reduced over the quad via shfl_xor.  tws stored with
// f-stride 17 so the lane-varying reads are bank-conflict-free.
__global__ __launch_bounds__(256) void k3_pern(
    const float* __restrict__ x, const float* __restrict__ ecol,
    const float* __restrict__ W1, const float* __restrict__ W2,
    const float* __restrict__ W3, const float* __restrict__ time_w,
    const float* __restrict__ time_b,
    float* __restrict__ xts, float* __restrict__ slhs,
    float* __restrict__ srhs, float* __restrict__ base) {
  __shared__ float tws[16 * 272];        // [o][f*17 + t2]
  __shared__ float W1s[16], W3s[16], Ecs[16], tbs[16], W2s[256];
  int tid = threadIdx.x;
  int b = blockIdx.y;
  for (int i = tid; i < 4096; i += 256) {
    int o = i >> 8, rem = i & 255, f = rem >> 4, t2 = rem & 15;
    tws[o * 272 + f * 17 + t2] = time_w[i];
  }
  W2s[tid] = W2[tid & 255];
  if (tid < 16) {
    W1s[tid] = W1[tid]; W3s[tid] = W3[tid];
    Ecs[tid] = ecol[b * 16 + tid]; tbs[tid] = time_b[tid];
  }
  __syncthreads();
  int q = tid & 3;
  int n = blockIdx.x * 64 + (tid >> 2);
  if (n >= Nn) return;                   // quad-uniform exit (same n per quad)
  const float* xr = x + ((size_t)b * Nn + n) * 256 + q * 64;
  float xtsv[4], slv[4], xw3[4], resid[4], to[16];
#pragma unroll
  for (int o = 0; o < 16; ++o) to[o] = 0.f;
#pragma unroll
  for (int fl = 0; fl < 4; ++fl) {
    int f = q * 4 + fl;
    float xf[16];
#pragma unroll
    for (int qq = 0; qq < 4; ++qq) {
      float4 v = *(const float4*)(xr + fl * 16 + qq * 4);
      xf[qq * 4 + 0] = v.x; xf[qq * 4 + 1] = v.y;
      xf[qq * 4 + 2] = v.z; xf[qq * 4 + 3] = v.w;
    }
    float a = 0, c = 0, d = 0;
#pragma unroll
    for (int t2 = 0; t2 < 16; ++t2) {
      a += Ecs[t2] * xf[t2];
      c += W1s[t2] * xf[t2];
      d += W3s[t2] * xf[t2];
    }
    xtsv[fl] = a; slv[fl] = c; xw3[fl] = d; resid[fl] = xf[15];
#pragma unroll
    for (int o = 0; o < 16; ++o) {
      float acc = 0;
#pragma unroll
      for (int t2 = 0; t2 < 16; ++t2) acc += tws[o * 272 + f * 17 + t2] * xf[t2];
      to[o] += acc;
    }
  }
  // reduce to[] over quad
#pragma unroll
  for (int m = 1; m < 4; m <<= 1)
#pragma unroll
    for (int o = 0; o < 16; ++o) to[o] += __shfl_xor(to[o], m, 64);
  // srhs partials over this quad's k2 range, then reduce
  float sg[16];
#pragma unroll
  for (int g = 0; g < 16; ++g) {
    float acc = 0;
#pragma unroll
    for (int k2l = 0; k2l < 4; ++k2l) acc += W2s[g * 16 + q * 4 + k2l] * xw3[k2l];
    sg[g] = acc;
  }
#pragma unroll
  for (int m = 1; m < 4; m <<= 1)
#pragma unroll
    for (int g = 0; g < 16; ++g) sg[g] += __shfl_xor(sg[g], m, 64);
  size_t o16 = ((size_t)b * Nn + n) * 16;
#pragma unroll
  for (int i = 0; i < 4; ++i) {
    int idx = q * 4 + i;
    xts[o16 + idx] = xtsv[i];
    slhs[o16 + idx] = slv[i];
    srhs[o16 + idx] = sg[idx];
    base[o16 + idx] = to[idx] + tbs[idx] + resid[i];
  }
}

// ---------------------------------------------------------------------------
// fconv2: fp32 -> fp16 bulk convert, both lap and bs in one launch (y=0/1).
__global__ __launch_bounds__(256) void fconv2(
    const float* __restrict__ s0, const float* __restrict__ s1,
    unsigned short* __restrict__ d0, unsigned short* __restrict__ d1) {
  size_t i = ((size_t)blockIdx.x * 256 + threadIdx.x) * 4;
  const float* src = blockIdx.y ? s1 : s0;
  unsigned short* dst = blockIdx.y ? d1 : d0;
  float4 v = *(const float4*)(src + i);
  u16x4 h;
  h.x = f2h(v.x); h.y = f2h(v.y); h.z = f2h(v.z); h.w = f2h(v.w);
  *(u16x4*)(dst + i) = h;
}

// ---------------------------------------------------------------------------
// vconv2: Vs (4000x4000 fp32) -> Vh (4096x4096 fp16), zero-padded both dims.
__global__ __launch_bounds__(256) void vconv2(
    const float* __restrict__ Vs, unsigned short* __restrict__ Vh) {
  int row = blockIdx.y;
  int col = blockIdx.x * 1024 + threadIdx.x * 4;
  u16x4 h;
  if (row < Nn && col < Nn) {  // col aligned: 4000 % 4 == 0
    float4 v = *(const float4*)(Vs + (size_t)row * Nn + col);
    h.x = f2h(v.x); h.y = f2h(v.y); h.z = f2h(v.z); h.w = f2h(v.w);
  } else {
    h.x = 0; h.y = 0; h.z = 0; h.w = 0;
  }
  *(u16x4*)(Vh + (size_t)row * KS + col) = h;
}

// ---------------------------------------------------------------------------
// tsconv_n: fused nrm + transpose-convert: v = ts[b,n,f]/lsum[b,n];
// write back normalized ts and tsT[(b*16+f)][n] fp16.
__global__ __launch_bounds__(256) void tsconv_n(
    float* __restrict__ ts, const float* __restrict__ lsum,
    unsigned short* __restrict__ tsT) {
  int n = blockIdx.x * 256 + threadIdx.x;
  int col = blockIdx.y;  // 0..63 = (b<<4)|f
  if (n >= Nn) return;
  int b = col >> 4, f = col & 15;
  size_t i = ((size_t)b * Nn + n) * 16 + f;
  float v = ts[i] / lsum[(size_t)b * Nn + n];
  ts[i] = v;
  tsT[(size_t)col * Nn + n] = f2h(v);
}

// ---------------------------------------------------------------------------
// tsconv: ts[b][n][f] fp32 -> tsT[(b*16+f)][n] fp16 (B-operand for chebm)
__global__ __launch_bounds__(256) void tsconv(
    const float* __restrict__ ts, unsigned short* __restrict__ tsT) {
  int n = blockIdx.x * 256 + threadIdx.x;
  int col = blockIdx.y;  // 0..63 = (b<<4)|f
  if (n >= Nn) return;
  int b = col >> 4, f = col & 15;
  tsT[(size_t)col * Nn + n] = f2h(ts[((size_t)b * Nn + n) * 16 + f]);
}

// ---------------------------------------------------------------------------
// GEMM1: P[m,k] = sigmoid(slhs[b,m]·srhs[b,k] + bs[m,k]); store P^T fp16
// with row stride KS (pad k-cols left poisoned; they multiply Vh's zero pad).
__global__ __launch_bounds__(256) void gemm1_P(
    const float* __restrict__ slhs, const float* __restrict__ srhs,
    const unsigned short* __restrict__ bsH, unsigned short* __restrict__ PhT, int b) {
  __shared__ float Ms[64][17];
  __shared__ float Cs[64][17];
  __shared__ float Pt[64][65];
  int tid = threadIdx.x;
  int m0 = blockIdx.y * 64, k0 = blockIdx.x * 64;
  int lr = tid >> 2, lq = (tid & 3) << 2;
  {
    int gm = m0 + lr; if (gm > Nn - 1) gm = Nn - 1;
    float4 v = *(const float4*)(slhs + ((size_t)b * Nn + gm) * 16 + lq);
    Ms[lr][lq + 0] = v.x; Ms[lr][lq + 1] = v.y; Ms[lr][lq + 2] = v.z; Ms[lr][lq + 3] = v.w;
    int gk = k0 + lr; if (gk > Nn - 1) gk = Nn - 1;
    float4 w = *(const float4*)(srhs + ((size_t)b * Nn + gk) * 16 + lq);
    Cs[lr][lq + 0] = w.x; Cs[lr][lq + 1] = w.y; Cs[lr][lq + 2] = w.z; Cs[lr][lq + 3] = w.w;
  }
  __syncthreads();
  int tx = tid & 15, ty = tid >> 4;
  float acc[4][4] = {};
#pragma unroll
  for (int f = 0; f < 16; ++f) {
    float a4[4], b4[4];
#pragma unroll
    for (int i = 0; i < 4; ++i) a4[i] = Ms[ty * 4 + i][f];
#pragma unroll
    for (int j = 0; j < 4; ++j) b4[j] = Cs[tx * 4 + j][f];
#pragma unroll
    for (int i = 0; i < 4; ++i)
#pragma unroll
      for (int j = 0; j < 4; ++j) acc[i][j] += a4[i] * b4[j];
  }
#pragma unroll
  for (int i = 0; i < 4; ++i) {
    int m = m0 + ty * 4 + i;
    int k = k0 + tx * 4;
    float bv[4] = {0.f, 0.f, 0.f, 0.f};
    if (m < Nn) {
      if (k + 3 < Nn) {
        u16x4 t4 = *(const u16x4*)(bsH + (size_t)m * Nn + k);
        bv[0] = h2f(t4.x); bv[1] = h2f(t4.y); bv[2] = h2f(t4.z); bv[3] = h2f(t4.w);
      } else {
        for (int j = 0; j < 4; ++j)
          if (k + j < Nn) bv[j] = h2f(bsH[(size_t)m * Nn + k + j]);
      }
    }
#pragma unroll
    for (int j = 0; j < 4; ++j) {
      float z = acc[i][j] + bv[j];
      Pt[ty * 4 + i][tx * 4 + j] = 1.f / (1.f + __expf(-z));
    }
  }
  __syncthreads();
#pragma unroll
  for (int i = 0; i < 4; ++i) {
    int kl = ty * 4 + i;
    int ml = tx * 4;
    int gm = m0 + ml;
    u16x4 h;
    h.x = f2h(Pt[ml + 0][kl]);
    h.y = f2h(Pt[ml + 1][kl]);
    h.z = f2h(Pt[ml + 2][kl]);
    h.w = f2h(Pt[ml + 3][kl]);
    size_t off = (size_t)(k0 + kl) * KS + gm;
    if (gm + 3 < Nn) {
      *(u16x4*)(PhT + off) = h;
    } else {
      unsigned short hv[4] = {h.x, h.y, h.z, h.w};
      for (int q = 0; q < 4; ++q)
        if (gm + q < Nn) PhT[off + q] = hv[q];
    }
  }
}

// ---------------------------------------------------------------------------
// GEMM2 (r7 verified, 152 us): 256x256 tile, 8-wave, 4-phase/K-tile, counted
// vmcnt, drain-at-END.  Phase = {ds_reads -> STG issue -> MFMA (compiler
// interleaves counted lgkm waits) -> lgkmcnt(0) -> [vmcnt(8) ph2/ph4] ->
// barrier}.  vmcnt ledger: vmcnt(12) prologue, vmcnt(8) at ph2/ph4.
// Bank-conflict-free swizzle (r4-verified): store granule g^((row>>1)&3) via
// pre-swizzled global source (linear LDS dest, m104); read gr=qd^((ml>>1)&3).
__global__ __launch_bounds__(512, 2) void gemm2_mfma(
    const unsigned short* __restrict__ Vh, const unsigned short* __restrict__ PhT,
    float* __restrict__ SP, unsigned int* __restrict__ rmaxu) {
  __shared__ unsigned short Ah[2][2][8192];
  __shared__ unsigned short Bh[2][2][8192];
  int t = threadIdx.x;
  int bid = blockIdx.x;
  int wg = (bid & 7) * 32 + (bid >> 3);       // bijective XCD swizzle (256%8==0)
  int row0 = (wg >> 4) * 256, col0 = (wg & 15) * 256;

  int sr = t >> 2, sg = t & 3;
  int ssw = sg ^ ((t >> 3) & 3);
  size_t a0 = (size_t)(row0 + sr) * KS + ssw * 8;
  size_t a1 = (size_t)(row0 + 128 + sr) * KS + ssw * 8;
  size_t b0 = (size_t)(col0 + sr) * KS + ssw * 8;
  size_t b1 = (size_t)(col0 + 128 + sr) * KS + ssw * 8;
  int ld0 = t * 8, ld1 = 4096 + t * 8;        // LDS dest short-index (lane-linear)

  int lane = t & 63, wid = t >> 6;
  int wm = (wid >> 2) * 128, wn = (wid & 3) * 64;
  int ml = lane & 15, qd = lane >> 4;
  int gr = qd ^ ((ml >> 1) & 3);
  int aro[8], bro[4];
#pragma unroll
  for (int i = 0; i < 8; ++i) aro[i] = (wm + ml + i * 16) * 32 + gr * 8;
#pragma unroll
  for (int j = 0; j < 4; ++j) bro[j] = (wn + ml + j * 16) * 32 + gr * 8;

  f32x4 acc[8][4] = {};

#define STG(P, X, bf, kh, o0, o1, kt)                          \
  do {                                                         \
    size_t c_ = (size_t)(kt) * 64 + (kh) * 32;                 \
    gld16(P + (o0) + c_, &X[bf][kh][ld0]);                     \
    gld16(P + (o1) + c_, &X[bf][kh][ld1]);                     \
  } while (0)
#define LGKM0() asm volatile("s_waitcnt lgkmcnt(0)" ::: "memory")
#define VM8()   asm volatile("s_waitcnt vmcnt(8)" ::: "memory")
#define BARR()  __builtin_amdgcn_s_barrier()

  // prologue: tiles 0 and 1 fully staged (16 loads)
  STG(Vh, Ah, 0, 0, a0, a1, 0); STG(PhT, Bh, 0, 0, b0, b1, 0);
  STG(Vh, Ah, 0, 1, a0, a1, 0); STG(PhT, Bh, 0, 1, b0, b1, 0);
  STG(Vh, Ah, 1, 0, a0, a1, 1); STG(PhT, Bh, 1, 0, b0, b1, 1);
  STG(Vh, Ah, 1, 1, a0, a1, 1); STG(PhT, Bh, 1, 1, b0, b1, 1);
  asm volatile("s_waitcnt vmcnt(12)" ::: "memory");  // kh0(0) landed
  BARR();

#pragma unroll 1
  for (int G = 0; G < 64; ++G) {
    int cb = G & 1, nb = cb ^ 1;
    int tn1 = (G + 1 < 64) ? G + 1 : 63;   // clamped dummy keeps vmcnt uniform
    int tn2 = (G + 2 < 64) ? G + 2 : 63;
    half8 av[4], bv[4];
    // ---- ph1: kh0 rows 0-3; STG A-kh1(tn1)
#pragma unroll
    for (int j = 0; j < 4; ++j) bv[j] = *(const half8*)&Bh[cb][0][bro[j]];
#pragma unroll
    for (int i = 0; i < 4; ++i) av[i] = *(const half8*)&Ah[cb][0][aro[i]];
    STG(Vh, Ah, nb, 1, a0, a1, tn1);
    __builtin_amdgcn_s_setprio(1);
#pragma unroll
    for (int i = 0; i < 4; ++i)
#pragma unroll
      for (int j = 0; j < 4; ++j)
        acc[i][j] = __builtin_amdgcn_mfma_f32_16x16x32_f16(av[i], bv[j], acc[i][j], 0, 0, 0);
    __builtin_amdgcn_s_setprio(0);
    LGKM0();
    BARR();
    // ---- ph2: kh0 rows 4-7 (reuse bv); STG B-kh1(tn1)
#pragma unroll
    for (int i = 0; i < 4; ++i) av[i] = *(const half8*)&Ah[cb][0][aro[4 + i]];
    STG(PhT, Bh, nb, 1, b0, b1, tn1);
    __builtin_amdgcn_s_setprio(1);
#pragma unroll
    for (int i = 0; i < 4; ++i)
#pragma unroll
      for (int j = 0; j < 4; ++j)
        acc[4 + i][j] = __builtin_amdgcn_mfma_f32_16x16x32_f16(av[i], bv[j], acc[4 + i][j], 0, 0, 0);
    __builtin_amdgcn_s_setprio(0);
    LGKM0();
    VM8();                              // kh1(G) landed
    BARR();
    // ---- ph3: kh1 rows 0-3; STG A-kh0(tn2)
#pragma unroll
    for (int j = 0; j < 4; ++j) bv[j] = *(const half8*)&Bh[cb][1][bro[j]];
#pragma unroll
    for (int i = 0; i < 4; ++i) av[i] = *(const half8*)&Ah[cb][1][aro[i]];
    STG(Vh, Ah, cb, 0, a0, a1, tn2);
    __builtin_amdgcn_s_setprio(1);
#pragma unroll
    for (int i = 0; i < 4; ++i)
#pragma unroll
      for (int j = 0; j < 4; ++j)
        acc[i][j] = __builtin_amdgcn_mfma_f32_16x16x32_f16(av[i], bv[j], acc[i][j], 0, 0, 0);
    __builtin_amdgcn_s_setprio(0);
    LGKM0();
    BARR();
    // ---- ph4: kh1 rows 4-7; STG B-kh0(tn2)
#pragma unroll
    for (int i = 0; i < 4; ++i) av[i] = *(const half8*)&Ah[cb][1][aro[4 + i]];
    STG(PhT, Bh, cb, 0, b0, b1, tn2);
    __builtin_amdgcn_s_setprio(1);
#pragma unroll
    for (int i = 0; i < 4; ++i)
#pragma unroll
      for (int j = 0; j < 4; ++j)
        acc[4 + i][j] = __builtin_amdgcn_mfma_f32_16x16x32_f16(av[i], bv[j], acc[4 + i][j], 0, 0, 0);
    __builtin_amdgcn_s_setprio(0);
    LGKM0();
    VM8();                              // kh0(G+1) landed
    BARR();
  }
#undef STG
#undef LGKM0
#undef VM8
#undef BARR

  // epilogue: C/D layout col=lane&15, row=(lane>>4)*4+reg [m89]; store + row max
#pragma unroll
  for (int i = 0; i < 8; ++i) {
#pragma unroll
    for (int r = 0; r < 4; ++r) {
      int grow = row0 + wm + i * 16 + qd * 4 + r;
      if (grow >= Nn) continue;
      float rowmax = -3.0e38f;
#pragma unroll
      for (int j = 0; j < 4; ++j) {
        int gcol = col0 + wn + j * 16 + ml;
        if (gcol < Nn) {
          float v = acc[i][j][r];
          SP[(size_t)grow * Nn + gcol] = v;
          rowmax = fmaxf(rowmax, v);
        }
      }
#pragma unroll
      for (int mk = 1; mk < 16; mk <<= 1)
        rowmax = fmaxf(rowmax, __shfl_xor(rowmax, mk, 64));
      if (ml == 0) {
        unsigned u = __float_as_uint(rowmax);
        u = (u & 0x80000000u) ? ~u : (u | 0x80000000u);
        atomicMax(rmaxu + grow, u);
      }
    }
  }
}

// ---------------------------------------------------------------------------
// txsum (MFMA): ts0[b,n,f] += sum_{k in chunk} exp(SP[n,k]-rm[n])*X[k,f]
__global__ __launch_bounds__(256) void txsum_sp(
    const float* __restrict__ SP, const float* __restrict__ xts,
    const unsigned int* __restrict__ rmaxu, float* __restrict__ lsum,
    float* __restrict__ ts0, int b) {
  __shared__ unsigned short XT[16][824];   // [f][k] fp16, pad->(<=2-way conflicts)
  int tid = threadIdx.x;
  int kbase = blockIdx.y * 800;            // 5 chunks x 800 = 4000, 800 = 25*32
  for (int i4 = tid; i4 < 3200; i4 += 256) {
    int k = i4 >> 2, f4 = (i4 & 3) << 2;
    float4 v = *(const float4*)(xts + ((size_t)b * Nn + kbase + k) * 16 + f4);
    XT[f4 + 0][k] = f2h(v.x); XT[f4 + 1][k] = f2h(v.y);
    XT[f4 + 2][k] = f2h(v.z); XT[f4 + 3][k] = f2h(v.w);
  }
  __syncthreads();
  int lane = tid & 63, wid = tid >> 6;
  int ml = lane & 15, qd = lane >> 4;
  int n0 = blockIdx.x * 64 + wid * 16;
  int nr = n0 + ml;
  int nrc = nr < Nn ? nr : Nn - 1;
  unsigned u = rmaxu[nrc];
  u = (u & 0x80000000u) ? (u ^ 0x80000000u) : ~u;
  float rm = __uint_as_float(u);
  const float* spr = SP + (size_t)nrc * Nn + kbase + qd * 8;
  f32x4 acc = {0.f, 0.f, 0.f, 0.f};
  float lpart = 0.f;
#pragma unroll 1
  for (int ks = 0; ks < 25; ++ks) {
    float4 v0 = *(const float4*)(spr + ks * 32);
    float4 v1 = *(const float4*)(spr + ks * 32 + 4);
    float e0 = __expf(v0.x - rm), e1 = __expf(v0.y - rm);
    float e2 = __expf(v0.z - rm), e3 = __expf(v0.w - rm);
    float e4 = __expf(v1.x - rm), e5 = __expf(v1.y - rm);
    float e6 = __expf(v1.z - rm), e7 = __expf(v1.w - rm);
    lpart += ((e0 + e1) + (e2 + e3)) + ((e4 + e5) + (e6 + e7));
    half8 a_h, b_h;
    a_h[0] = (_Float16)e0; a_h[1] = (_Float16)e1;
    a_h[2] = (_Float16)e2; a_h[3] = (_Float16)e3;
    a_h[4] = (_Float16)e4; a_h[5] = (_Float16)e5;
    a_h[6] = (_Float16)e6; a_h[7] = (_Float16)e7;
    b_h = *(const half8*)&XT[ml][ks * 32 + qd * 8];
    acc = __builtin_amdgcn_mfma_f32_16x16x32_f16(a_h, b_h, acc, 0, 0, 0);
  }
  lpart += __shfl_xor(lpart, 16, 64);
  lpart += __shfl_xor(lpart, 32, 64);
  if (qd == 0 && nr < Nn) atomicAdd(&lsum[nr], lpart);
#pragma unroll
  for (int r = 0; r < 4; ++r) {
    int n = n0 + qd * 4 + r;
    if (n < Nn) atomicAdd(&ts0[((size_t)b * Nn + n) * 16 + ml], acc[r]);
  }
}

// ---------------------------------------------------------------------------
// chebm (r9: double-buffered, counted vmcnt): Cout += lapH·tsT^T over chunk.
// Per iter: always-stage next tile into alternate buf (dummy overread on the
// final iter lands in adjacent ws / never-read buffer); vmcnt(2) + barrier
// (never drains the prefetch); compute; lgkm0 + barrier (WAR for next stage).
__global__ __launch_bounds__(256) void chebm(
    const unsigned short* __restrict__ lapH, const unsigned short* __restrict__ tsT,
    float* __restrict__ Cout) {
  __shared__ unsigned short Ah[2][2048];
  __shared__ unsigned short Bh[2][2048];
  int t = threadIdx.x;
  int row0 = blockIdx.x * 64;
  int kc0 = blockIdx.y * 25 * 32;
  int kc1 = kc0 + 25 * 32;
  int arow = row0 + (t >> 2); if (arow > Nn - 1) arow = Nn - 1;
  size_t a_base = (size_t)arow * Nn + (t & 3) * 8;
  size_t b_base = (size_t)(t >> 2) * Nn + (t & 3) * 8;

  int lane = t & 63;
  int wid = t >> 6;
  int wm = (wid >> 1) * 32, wn = (wid & 1) * 32;
  int ml = lane & 15, qd = lane >> 4;
  int aoff = (wm + ml) * 32 + qd * 8;
  int boff = (wn + ml) * 32 + qd * 8;

  f32x4 acc[2][2] = {};

  // prologue: stage tile 0
  gld16(lapH + a_base + kc0, &Ah[0][t * 8]);
  gld16(tsT + b_base + kc0, &Bh[0][t * 8]);
  int cur = 0;
#pragma unroll 1
  for (int k0 = kc0; k0 < kc1; k0 += 32) {
    int nxt = cur ^ 1;
    // always-stage next (unclamped: final overread lands in ws, buf unread)
    gld16(lapH + a_base + k0 + 32, &Ah[nxt][t * 8]);
    gld16(tsT + b_base + k0 + 32, &Bh[nxt][t * 8]);
    asm volatile("s_waitcnt vmcnt(2)" ::: "memory");  // tile(cur) landed
    __builtin_amdgcn_s_barrier();
    half8 a_h[2], b_h[2];
#pragma unroll
    for (int i = 0; i < 2; ++i) a_h[i] = *(const half8*)&Ah[cur][aoff + i * 512];
#pragma unroll
    for (int j = 0; j < 2; ++j) b_h[j] = *(const half8*)&Bh[cur][boff + j * 512];
#pragma unroll
    for (int i = 0; i < 2; ++i)
#pragma unroll
      for (int j = 0; j < 2; ++j)
        acc[i][j] = __builtin_amdgcn_mfma_f32_16x16x32_f16(a_h[i], b_h[j], acc[i][j], 0, 0, 0);
    asm volatile("s_waitcnt lgkmcnt(0)" ::: "memory");
    __builtin_amdgcn_s_barrier();       // WAR: all reads of cur done before next STG
    cur = nxt;
  }
#pragma unroll
  for (int i = 0; i < 2; ++i)
#pragma unroll
    for (int j = 0; j < 2; ++j) {
      int gcol = wn + j * 16 + ml;
      int b = gcol >> 4, f = gcol & 15;
#pragma unroll
      for (int r = 0; r < 4; ++r) {
        int grow = row0 + wm + i * 16 + qd * 4 + r;
        if (grow < Nn) {
          size_t idx = ((size_t)b * Nn + grow) * 16 + f;
          atomicAdd(&Cout[idx], acc[i][j][r]);
        }
      }
    }
}

// ---------------------------------------------------------------------------
// K_y: Chebyshev recombination with split-K-raw ts2 (ts2raw = lap·ts1):
//   Tx2 = 2·lap·Tx1 − Tx0  =>  contribution T0·(CW0−CW2) + T1·CW1 + 2·T2raw·CW2
// y = (1/16)*sum + base ; accumulate LN stats
__global__ __launch_bounds__(256) void ky_k(
    const float* __restrict__ ts0, const float* __restrict__ ts1,
    const float* __restrict__ ts2, const float* __restrict__ cw,
    const float* __restrict__ base, float* __restrict__ ybuf,
    float* __restrict__ lnacc) {
  __shared__ float T0[256], T1[256], T2[256], CW[768];
  __shared__ float rs[256], rq[256];
  int tid = threadIdx.x;
  int b = blockIdx.y;
  size_t base_i = ((size_t)b * Nn + blockIdx.x * 16) * 16;
  T0[tid] = ts0[base_i + tid];
  T1[tid] = ts1[base_i + tid];
  T2[tid] = ts2[base_i + tid];
  for (int i = tid; i < 768; i += 256) CW[i] = cw[i];
  __syncthreads();
  int r = tid >> 4, o = tid & 15;
  float acc = 0.f;
#pragma unroll
  for (int f2 = 0; f2 < 16; ++f2) {
    float c2 = CW[512 + f2 * 16 + o];
    acc += T0[r * 16 + f2] * (CW[f2 * 16 + o] - c2);
    acc += T1[r * 16 + f2] * CW[256 + f2 * 16 + o];
    acc += (2.0f * T2[r * 16 + f2]) * c2;
  }
  float y = acc * 0.0625f + base[base_i + tid];
  ybuf[base_i + tid] = y;
  rs[tid] = y; rq[tid] = y * y;
  __syncthreads();
  for (int s2 = 128; s2 > 0; s2 >>= 1) {
    if (tid < s2) { rs[tid] += rs[tid + s2]; rq[tid] += rq[tid + s2]; }
    __syncthreads();
  }
  if (tid == 0) {
    atomicAdd(&lnacc[b * 2 + 0], rs[0]);
    atomicAdd(&lnacc[b * 2 + 1], rq[0]);
  }
}

// ---------------------------------------------------------------------------
// K_ln: layernorm over (N,O) per batch + relu
__global__ __launch_bounds__(256) void kln_k(
    const float* __restrict__ ybuf, const float* __restrict__ lnacc,
    const float* __restrict__ lg, const float* __restrict__ lb,
    float* __restrict__ outp) {
  int tid = threadIdx.x;
  int b = blockIdx.y;
  size_t i = ((size_t)b * Nn + blockIdx.x * 16) * 16 + tid;
  size_t nz = (size_t)blockIdx.x * 256 + tid;
  const float inv = 1.0f / 64000.0f;
  float s = lnacc[b * 2 + 0], q = lnacc[b * 2 + 1];
  float mean = s * inv;
  float var = q * inv - mean * mean;
  float rstd = rsqrtf(var + 1e-5f);
  float v = (ybuf[i] - mean) * rstd * lg[nz] + lb[nz];
  outp[i] = fmaxf(v, 0.f);
}

// ---------------------------------------------------------------------------
extern "C" void kernel_launch(void* const* d_in, const int* in_sizes, int n_in,
                              void* d_out, int out_size, void* d_ws, size_t ws_size,
                              hipStream_t stream) {
  const float* x   = (const float*)d_in[0];
  const float* lap = (const float*)d_in[1];
  const float* W1  = (const float*)d_in[2];
  const float* W2  = (const float*)d_in[3];
  const float* W3  = (const float*)d_in[4];
  const float* bs  = (const float*)d_in[5];
  const float* Vs  = (const float*)d_in[6];
  const float* U1  = (const float*)d_in[7];
  const float* U2  = (const float*)d_in[8];
  const float* U3  = (const float*)d_in[9];
  const float* be  = (const float*)d_in[10];
  const float* Ve  = (const float*)d_in[11];
  const float* cw  = (const float*)d_in[12];
  const float* tw  = (const float*)d_in[13];
  const float* tb  = (const float*)d_in[14];
  const float* lg  = (const float*)d_in[15];
  const float* lb  = (const float*)d_in[16];
  float* ws = (float*)d_ws;
  float* SP = ws;  // NP floats
  unsigned short* Vh   = (unsigned short*)(ws + (size_t)NP);       // 4096*4096
  unsigned short* PhT  = Vh + (size_t)KS * KS;                     // 4096*4096
  unsigned short* lapH = PhT + (size_t)KS * KS;                    // 4000*4000
  unsigned short* bsH  = lapH + (size_t)Nn * Nn;                   // 4000*4000
  unsigned short* tsT  = bsH + (size_t)Nn * Nn;                    // 64*4000
  float* xts  = (float*)(tsT + 64 * Nn + 64);
  float* slhs = xts + 256000;
  float* srhs = slhs + 256000;
  float* base = srhs + 256000;
  float* ts0  = base + 256000;
  float* ts1  = ts0 + 256000;
  float* ts2  = ts1 + 256000;
  float* ybuf = ts2 + 256000;
  float* tl   = ybuf + 256000;  // B*16
  float* tr   = tl + 64;
  float* ecol = tr + 64;
  unsigned int* rmaxu = (unsigned int*)(ecol + 64);  // B*N
  float* lsum = (float*)(rmaxu + Bc * Nn);           // B*N
  float* lnacc = lsum + Bc * Nn;                     // B*2

  hipMemsetAsync(tl, 0, 128 * sizeof(float), stream);
  hipMemsetAsync(lnacc, 0, 8 * sizeof(float), stream);
  hipMemsetAsync(ts0, 0, 256000 * sizeof(float), stream);
  hipMemsetAsync(ts1, 0, 256000 * sizeof(float), stream);
  hipMemsetAsync(ts2, 0, 256000 * sizeof(float), stream);
  hipMemsetAsync(rmaxu, 0, Bc * Nn * sizeof(unsigned int), stream);
  hipMemsetAsync(lsum, 0, Bc * Nn * sizeof(float), stream);

  k1_trhs<<<dim3(63, 4), 256, 0, stream>>>(x, U1, U2, U3, tl, tr);
  k2_eattn<<<dim3(4), 256, 0, stream>>>(tl, tr, be, Ve, ecol);
  k3_pern<<<dim3(63, 4), 256, 0, stream>>>(x, ecol, W1, W2, W3, tw, tb,
                                           xts, slhs, srhs, base);
  vconv2<<<dim3(4, 4096), 256, 0, stream>>>(Vs, Vh);
  fconv2<<<dim3(15625, 2), 256, 0, stream>>>(lap, bs, lapH, bsH);
  for (int b = 0; b < 4; ++b) {
    gemm1_P<<<dim3(63, 63), 256, 0, stream>>>(slhs, srhs, bsH, PhT, b);
    gemm2_mfma<<<dim3(256), 512, 0, stream>>>(Vh, PhT, SP, rmaxu + b * Nn);
    txsum_sp<<<dim3(63, 5), 256, 0, stream>>>(SP, xts, rmaxu + b * Nn,
                                              lsum + b * Nn, ts0, b);
  }
  tsconv_n<<<dim3(16, 64), 256, 0, stream>>>(ts0, lsum, tsT);
  chebm<<<dim3(63, 5), 256, 0, stream>>>(lapH, tsT, ts1);
  tsconv<<<dim3(16, 64), 256, 0, stream>>>(ts1, tsT);
  chebm<<<dim3(63, 5), 256, 0, stream>>>(lapH, tsT, ts2);
  ky_k<<<dim3(250, 4), 256, 0, stream>>>(ts0, ts1, ts2, cw, base, ybuf, lnacc);
  kln_k<<<dim3(250, 4), 256, 0, stream>>>(ybuf, lnacc, lg, lb, (float*)d_out);
}